// Round 1
// baseline (641.446 us; speedup 1.0000x reference)
//
#include <hip/hip_runtime.h>

namespace {
constexpr int TK  = 17;
constexpr int TC  = 256;
constexpr int TCI = 64;
constexpr int TG  = 5;
constexpr int XPAD = 4;   // row pad (floats) to spread LDS banks

__device__ __forceinline__ float fsilu(float v)    { return v / (1.f + __expf(-v)); }
__device__ __forceinline__ float fsigmoid(float v) { return 1.f / (1.f + __expf(-v)); }
}

__global__ __launch_bounds__(256, 4)
void fused_gnn_kernel(const float* __restrict__ x,
                      const float* __restrict__ Wd,
                      const float* __restrict__ bd,
                      const float* __restrict__ bn1s, const float* __restrict__ bn1b,
                      const float* __restrict__ bn1m, const float* __restrict__ bn1v,
                      const float* __restrict__ Wc,
                      const float* __restrict__ bn2s, const float* __restrict__ bn2b,
                      const float* __restrict__ bn2m, const float* __restrict__ bn2v,
                      const float* __restrict__ Wa, const float* __restrict__ ba,
                      float* __restrict__ out)
{
    __shared__ float xs[TK][TC + XPAD];        // staged x tile, reused in phase F
    __shared__ float xd_s[TK][TCI + XPAD];     // silu(bn1(x@Wd))
    __shared__ float means_s[TG][TCI];
    __shared__ float mw_s[2][TG][TCI];         // mw1, mw2
    __shared__ float agg_s[TG][TCI];

    const int tid = threadIdx.x;
    const int b   = blockIdx.x;
    const float* xb = x + (size_t)b * (TK * TC);

    // ---- stage x (17x256) as float4, coalesced ----
    for (int idx = tid; idx < TK * TC / 4; idx += 256) {
        const int k  = idx >> 6;      // 64 float4 per row
        const int c4 = idx & 63;
        *(float4*)&xs[k][c4 * 4] = ((const float4*)xb)[idx];
    }
    __syncthreads();

    const int lane = tid & 63;
    const int wv   = tid >> 6;            // wave 0..3
    const int ksub = lane >> 4;           // 0..3  (4 k-rows per wave)
    const int k    = wv * 4 + ksub;       // 0..15 (k=16 handled by wave 0)
    const int i4   = (lane & 15) * 4;     // 4 consecutive i per lane

    // ---- Phase A: xd[k][i] = sum_c x[k][c] * Wd[c][i] ----
    float acc0 = 0.f, acc1 = 0.f, acc2 = 0.f, acc3 = 0.f;
    float g0 = 0.f, g1 = 0.f, g2 = 0.f, g3 = 0.f;   // k = 16 (wave 0)
    #pragma unroll 8
    for (int c4 = 0; c4 < TC; c4 += 4) {
        const float4 xv = *(const float4*)&xs[k][c4];
        const float4 wA = *(const float4*)&Wd[(c4 + 0) * TCI + i4];
        const float4 wB = *(const float4*)&Wd[(c4 + 1) * TCI + i4];
        const float4 wC = *(const float4*)&Wd[(c4 + 2) * TCI + i4];
        const float4 wD = *(const float4*)&Wd[(c4 + 3) * TCI + i4];
        acc0 += xv.x * wA.x + xv.y * wB.x + xv.z * wC.x + xv.w * wD.x;
        acc1 += xv.x * wA.y + xv.y * wB.y + xv.z * wC.y + xv.w * wD.y;
        acc2 += xv.x * wA.z + xv.y * wB.z + xv.z * wC.z + xv.w * wD.z;
        acc3 += xv.x * wA.w + xv.y * wB.w + xv.z * wC.w + xv.w * wD.w;
        if (wv == 0) {
            const float4 xw = *(const float4*)&xs[16][c4];
            g0 += xw.x * wA.x + xw.y * wB.x + xw.z * wC.x + xw.w * wD.x;
            g1 += xw.x * wA.y + xw.y * wB.y + xw.z * wC.y + xw.w * wD.y;
            g2 += xw.x * wA.z + xw.y * wB.z + xw.z * wC.z + xw.w * wD.z;
            g3 += xw.x * wA.w + xw.y * wB.w + xw.z * wC.w + xw.w * wD.w;
        }
    }
    // bn1 + silu epilogue (fold b_down into bn1 affine)
    {
        const float4 s1  = *(const float4*)&bn1s[i4];
        const float4 v1  = *(const float4*)&bn1v[i4];
        const float4 m1  = *(const float4*)&bn1m[i4];
        const float4 bb1 = *(const float4*)&bn1b[i4];
        const float4 bd4 = *(const float4*)&bd[i4];
        const float a1x = s1.x * rsqrtf(v1.x + 1e-5f);
        const float a1y = s1.y * rsqrtf(v1.y + 1e-5f);
        const float a1z = s1.z * rsqrtf(v1.z + 1e-5f);
        const float a1w = s1.w * rsqrtf(v1.w + 1e-5f);
        const float b1x = (bd4.x - m1.x) * a1x + bb1.x;
        const float b1y = (bd4.y - m1.y) * a1y + bb1.y;
        const float b1z = (bd4.z - m1.z) * a1z + bb1.z;
        const float b1w = (bd4.w - m1.w) * a1w + bb1.w;
        float4 r;
        r.x = fsilu(acc0 * a1x + b1x);
        r.y = fsilu(acc1 * a1y + b1y);
        r.z = fsilu(acc2 * a1z + b1z);
        r.w = fsilu(acc3 * a1w + b1w);
        *(float4*)&xd_s[k][i4] = r;
        if (wv == 0 && lane < 16) {
            float4 r2;
            r2.x = fsilu(g0 * a1x + b1x);
            r2.y = fsilu(g1 * a1y + b1y);
            r2.z = fsilu(g2 * a1z + b1z);
            r2.w = fsilu(g3 * a1w + b1w);
            *(float4*)&xd_s[16][i4] = r2;
        }
    }
    __syncthreads();

    // ---- Phase B1: group means (g is wave-uniform in both passes) ----
    for (int u = tid; u < TG * TCI; u += 256) {
        const int g = u >> 6, i = u & 63;
        float m;
        if (g == 0) {
            m = (xd_s[0][i] + xd_s[1][i] + xd_s[2][i] + xd_s[3][i] + xd_s[4][i]) * 0.2f;
        } else {
            const int base = (g == 1) ? 5 : (g == 2) ? 6 : (g == 3) ? 11 : 12;
            m = (xd_s[base][i] + xd_s[base + 2][i] + xd_s[base + 4][i]) * (1.f / 3.f);
        }
        means_s[g][i] = m;
    }
    __syncthreads();

    // ---- Phase B2: mw1[g][o] = means[g] . Wc[o][0:64]; mw2 over Wc[o][64:128] ----
    for (int u = tid; u < 2 * TG * TCI; u += 256) {
        const int which = (u >= TG * TCI) ? 1 : 0;
        const int rem   = u - which * TG * TCI;
        const int g = rem >> 6, o = rem & 63;
        const float4* wrow = (const float4*)&Wc[o * (2 * TCI) + which * TCI];
        const float4* mrow = (const float4*)&means_s[g][0];
        float s = 0.f;
        #pragma unroll
        for (int t = 0; t < TCI / 4; ++t) {
            const float4 w4 = wrow[t];
            const float4 m4 = mrow[t];
            s += m4.x * w4.x + m4.y * w4.y + m4.z * w4.z + m4.w * w4.w;
        }
        mw_s[which][g][o] = s;
    }
    __syncthreads();

    // ---- Phase B3: agg[g][o] = sum_{c!=g} silu(bn2(mw1[g]-mw2[g]+mw2[c])) ----
    for (int u = tid; u < TG * TCI; u += 256) {
        const int g = u >> 6, o = u & 63;
        const float a2 = bn2s[o] * rsqrtf(bn2v[o] + 1e-5f);
        const float b2 = bn2b[o] - bn2m[o] * a2;
        const float base = mw_s[0][g][o] - mw_s[1][g][o];
        float s = 0.f;
        #pragma unroll
        for (int cc = 0; cc < TG; ++cc) {
            if (cc == g) continue;
            const float z = (base + mw_s[1][cc][o]) * a2 + b2;
            s += fsilu(z);
        }
        agg_s[g][o] = s;
    }
    __syncthreads();

    // ---- Phase E: att[g][c] = sigmoid(agg[g] . Wa[:,c] + ba[c]) ----
    const int c = tid;
    float e0 = 0.f, e1 = 0.f, e2 = 0.f, e3 = 0.f, e4 = 0.f;
    #pragma unroll 8
    for (int i = 0; i < TCI; ++i) {
        const float w = Wa[i * TC + c];
        e0 += agg_s[0][i] * w;
        e1 += agg_s[1][i] * w;
        e2 += agg_s[2][i] * w;
        e3 += agg_s[3][i] * w;
        e4 += agg_s[4][i] * w;
    }
    const float bac = ba[c];
    float att[TG];
    att[0] = fsigmoid(e0 + bac);
    att[1] = fsigmoid(e1 + bac);
    att[2] = fsigmoid(e2 + bac);
    att[3] = fsigmoid(e3 + bac);
    att[4] = fsigmoid(e4 + bac);

    // ---- Phase F: out[k][c] = x[k][c] * att[group(k)][c] ----
    float* ob = out + (size_t)b * (TK * TC);
    constexpr int GOF[TK] = {0,0,0,0,0, 1,2,1,2,1, 2,3,4,3,4, 3,4};
    #pragma unroll
    for (int kk = 0; kk < TK; ++kk) {
        ob[kk * TC + c] = xs[kk][c] * att[GOF[kk]];
    }
}

extern "C" void kernel_launch(void* const* d_in, const int* in_sizes, int n_in,
                              void* d_out, int out_size, void* d_ws, size_t ws_size,
                              hipStream_t stream) {
    (void)n_in; (void)out_size; (void)d_ws; (void)ws_size;
    const float* x   = (const float*)d_in[0];
    const float* Wd  = (const float*)d_in[1];
    const float* bd  = (const float*)d_in[2];
    const float* s1  = (const float*)d_in[3];
    const float* b1  = (const float*)d_in[4];
    const float* m1  = (const float*)d_in[5];
    const float* v1  = (const float*)d_in[6];
    const float* Wc  = (const float*)d_in[7];
    const float* s2  = (const float*)d_in[8];
    const float* b2  = (const float*)d_in[9];
    const float* m2  = (const float*)d_in[10];
    const float* v2  = (const float*)d_in[11];
    const float* Wa  = (const float*)d_in[12];
    const float* ba  = (const float*)d_in[13];

    const int B = in_sizes[0] / (17 * 256);
    fused_gnn_kernel<<<B, 256, 0, stream>>>(x, Wd, bd, s1, b1, m1, v1,
                                            Wc, s2, b2, m2, v2, Wa, ba,
                                            (float*)d_out);
}